// Round 8
// baseline (968.463 us; speedup 1.0000x reference)
//
#include <hip/hip_runtime.h>
#include <math.h>

#define HID 4096
#define NH 32
#define DK 128
#define DV 128
#define NQKV 12288              // NH*DK*2 + NH*DV

// grid decomposition
#define NQKVAB_GRP 3088         // 3072 qkv groups + 16 a/b groups
#define NZ_GRP 1024             // z groups
#define NGRID 4112              // total blocks
#define K23_BLKS 512            // blocks that continue into phases 2+3

// d_out layout: [result 4096 | S 32*128*128=524288 | new_conv_state 12288*3=36864]
#define OUT_S_OFF 4096
#define OUT_CONV_OFF 528384

// ws layout (floats): [qkv 12288 | z 4096 | a 32 | b 32 | o 4096 | ctrs]
#define WS_Z_OFF 12288
#define WS_A_OFF 16384
#define WS_B_OFF 16416
#define WS_O_OFF 16448
// counters (bytes, 64B-aligned, past o-region end 82176)
#define CTR_QKVAB_B 82240
#define CTR_Z_B 82304
#define CTR_2_B 82368

typedef float f32x4 __attribute__((ext_vector_type(4)));
typedef float f32x2 __attribute__((ext_vector_type(2)));

__device__ __forceinline__ float wave_reduce_sum(float x) {
#pragma unroll
  for (int off = 32; off > 0; off >>= 1) x += __shfl_xor(x, off, 64);
  return x;
}

__device__ __forceinline__ float silu_f(float x) {
  return x / (1.f + __expf(-x));
}

__device__ __forceinline__ void spin_until(volatile unsigned int* c, unsigned int tgt) {
  while (__hip_atomic_load((const unsigned int*)c, __ATOMIC_RELAXED,
                           __HIP_MEMORY_SCOPE_AGENT) < tgt)
    __builtin_amdgcn_s_sleep(2);
}

__global__ __launch_bounds__(256, 4) void k_all(
    const float* __restrict__ hs, const float* __restrict__ delta_state,
    const float* __restrict__ conv_state, const float* __restrict__ Wqkv,
    const float* __restrict__ Wz, const float* __restrict__ Wa,
    const float* __restrict__ Wb, const float* __restrict__ Wout,
    const float* __restrict__ conv_w, const float* __restrict__ A_log,
    const float* __restrict__ dt_bias, const float* __restrict__ rms_w,
    float* __restrict__ ws, float* __restrict__ dout) {
  __shared__ __align__(16) float smem[HID];     // hs (ph1), g (ph3)
  __shared__ __align__(16) float qn[DK];
  __shared__ __align__(16) float kn[DK];
  __shared__ float va8[8];
  __shared__ float scale_s[NH];
  __shared__ float s_eg, s_beta, s_kq, s_rq, s_rk;

  unsigned int* c_qkvab = (unsigned int*)((char*)ws + CTR_QKVAB_B);
  unsigned int* c_z     = (unsigned int*)((char*)ws + CTR_Z_B);
  unsigned int* c_2     = (unsigned int*)((char*)ws + CTR_2_B);

  const int t = threadIdx.x;
  const int b = blockIdx.x;
  const int wave = t >> 6, lane = t & 63;

  // ---- stage hs to LDS ----
  {
    f32x4* hl4w = (f32x4*)smem;
    const f32x4* h4 = (const f32x4*)hs;
#pragma unroll
    for (int m = 0; m < 4; ++m) hl4w[m * 256 + t] = h4[m * 256 + t];
  }
  __syncthreads();
  const f32x4* __restrict__ hl4 = (const f32x4*)smem;

  // ---------------- Phase 1: one matvec row-group per block ----------------
  {
    int row; const float* W; int r;
    if (b < 3072) { row = b * 4 + wave; W = Wqkv; r = row; }
    else if (b < NQKVAB_GRP) {
      const int rl = (b - 3072) * 4 + wave;      // 0..63
      row = 16384 + rl;
      if (rl < 32) { W = Wa; r = rl; } else { W = Wb; r = rl - 32; }
    } else {
      const int rl = (b - NQKVAB_GRP) * 4 + wave;
      row = WS_Z_OFF + rl; W = Wz; r = rl;
    }
    const f32x4* __restrict__ Wr = (const f32x4*)(W + (size_t)r * HID);
    float acc0 = 0.f, acc1 = 0.f;
#pragma unroll
    for (int j = 0; j < 16; j += 2) {
      const f32x4 w0 = __builtin_nontemporal_load(&Wr[lane + j * 64]);
      const f32x4 h0 = hl4[lane + j * 64];
      const f32x4 w1 = __builtin_nontemporal_load(&Wr[lane + (j + 1) * 64]);
      const f32x4 h1 = hl4[lane + (j + 1) * 64];
      acc0 += w0.x * h0.x + w0.y * h0.y + w0.z * h0.z + w0.w * h0.w;
      acc1 += w1.x * h1.x + w1.y * h1.y + w1.z * h1.z + w1.w * h1.w;
    }
    const float acc = wave_reduce_sum(acc0 + acc1);
    if (lane == 0) {
      ws[row] = acc;
      if (b < 3072) {
        dout[OUT_CONV_OFF + row * 3 + 0] = conv_state[row * 3 + 1];
        dout[OUT_CONV_OFF + row * 3 + 1] = conv_state[row * 3 + 2];
        dout[OUT_CONV_OFF + row * 3 + 2] = acc;
      }
    }
  }
  __threadfence();          // release: ws row visible agent-wide
  __syncthreads();
  if (t == 0) {
    if (b < NQKVAB_GRP) atomicAdd(c_qkvab, 1u);
    else atomicAdd(c_z, 1u);
  }
  if (b >= K23_BLKS) return;     // 3600 blocks exit; 512 continue

  // ---------------- barrier: wait for all qkv/a/b rows ----------------
  if (t == 0) spin_until(c_qkvab, NQKVAB_GRP);
  __syncthreads();
  __threadfence();          // acquire: invalidate stale L1/L2

  // ---------------- Phase 2: delta-rule, head h, 8 v-rows ----------------
  {
    const int h = b >> 4;
    const int vbase = (b & 15) * 8;
    {
      const int seg = t >> 7, li = t & 127;
      const int row = seg * 4096 + h * 128 + li;
      const float c0 = conv_state[row * 3 + 0];
      const float c1 = conv_state[row * 3 + 1];
      const float c2v = conv_state[row * 3 + 2];
      const float w0 = conv_w[row * 4 + 0], w1 = conv_w[row * 4 + 1];
      const float w2 = conv_w[row * 4 + 2], w3 = conv_w[row * 4 + 3];
      const float co = w0 * c0 + w1 * c1 + w2 * c2v + w3 * ws[row];
      const float act = silu_f(co);
      if (seg == 0) qn[li] = act; else kn[li] = act;
    }
    if (t < 8) {
      const int row = 2 * 4096 + h * 128 + vbase + t;
      const float c0 = conv_state[row * 3 + 0];
      const float c1 = conv_state[row * 3 + 1];
      const float c2v = conv_state[row * 3 + 2];
      const float w0 = conv_w[row * 4 + 0], w1 = conv_w[row * 4 + 1];
      const float w2 = conv_w[row * 4 + 2], w3 = conv_w[row * 4 + 3];
      va8[t] = silu_f(w0 * c0 + w1 * c1 + w2 * c2v + w3 * ws[row]);
    }
    if (t == 8) {
      const float aa = ws[WS_A_OFF + h] + dt_bias[h];
      s_eg = __expf(-__expf(A_log[h]) * log1pf(__expf(aa)));
      s_beta = 1.f / (1.f + __expf(-ws[WS_B_OFF + h]));
    }
    __syncthreads();

    if (t < 64) {
      const float q0 = qn[t], q1 = qn[t + 64];
      const float k0 = kn[t], k1 = kn[t + 64];
      float sq = q0 * q0 + q1 * q1;
      float sk = k0 * k0 + k1 * k1;
      float dq = q0 * k0 + q1 * k1;
#pragma unroll
      for (int off = 32; off > 0; off >>= 1) {
        sq += __shfl_xor(sq, off, 64);
        sk += __shfl_xor(sk, off, 64);
        dq += __shfl_xor(dq, off, 64);
      }
      if (t == 0) {
        const float rq = rsqrtf(sq + 1e-6f) * 0.08838834764831845f; // *1/sqrt(DK)
        const float rk = rsqrtf(sk + 1e-6f);
        s_rq = rq; s_rk = rk;
        s_kq = dq * rq * rk;
      }
    }
    __syncthreads();
    if (t < 128) { qn[t] *= s_rq; kn[t] *= s_rk; }
    __syncthreads();

    const float eg = s_eg;
    const f32x2 kk = ((const f32x2*)kn)[lane];
    const f32x2 qq = ((const f32x2*)qn)[lane];
#pragma unroll
    for (int vv = 0; vv < 2; ++vv) {
      const int v = vbase + vv * 4 + wave;
      const size_t roff = ((size_t)h * DV + v) * DK;
      const f32x2 s2 = __builtin_nontemporal_load(
          &((const f32x2*)(delta_state + roff))[lane]);
      float r1 = s2.x * kk.x + s2.y * kk.y;
      float r2 = s2.x * qq.x + s2.y * qq.y;
#pragma unroll
      for (int off = 32; off > 0; off >>= 1) {
        r1 += __shfl_xor(r1, off, 64);
        r2 += __shfl_xor(r2, off, 64);
      }
      const float dv_ = s_beta * (va8[vv * 4 + wave] - eg * r1);
      const float o = eg * r2 + dv_ * s_kq;
      f32x2 out2;
      out2.x = eg * s2.x + dv_ * kk.x;
      out2.y = eg * s2.y + dv_ * kk.y;
      __builtin_nontemporal_store(out2, &((f32x2*)(dout + OUT_S_OFF + roff))[lane]);
      if (lane == 0) ws[WS_O_OFF + h * DV + v] = o;
    }
  }
  __threadfence();
  __syncthreads();
  if (t == 0) atomicAdd(c_2, 1u);

  // ---------------- barrier: wait for all o and all z ----------------
  if (t == 0) { spin_until(c_2, K23_BLKS); spin_until(c_z, NZ_GRP); }
  __syncthreads();
  __threadfence();

  // ---------------- Phase 3: gating + W_out matvec (8 rows/block) ----------
  {
    const int hh = t >> 3, sub = t & 7;
    const f32x4* o4 = (const f32x4*)(ws + WS_O_OFF + hh * 128 + sub * 16);
    float ssum = 0.f;
#pragma unroll
    for (int j = 0; j < 4; ++j) {
      const f32x4 o = o4[j];
      ssum += o.x * o.x + o.y * o.y + o.z * o.z + o.w * o.w;
    }
    ssum += __shfl_xor(ssum, 1, 64);
    ssum += __shfl_xor(ssum, 2, 64);
    ssum += __shfl_xor(ssum, 4, 64);
    if (sub == 0) scale_s[hh] = rsqrtf(ssum * (1.f / 128.f) + 1e-6f);
  }
  __syncthreads();
  {
    const f32x4* o4 = (const f32x4*)(ws + WS_O_OFF);
    const f32x4* z4 = (const f32x4*)(ws + WS_Z_OFF);
    const f32x4* r4 = (const f32x4*)rms_w;
    f32x4* g4w = (f32x4*)smem;
#pragma unroll
    for (int j = 0; j < 4; ++j) {
      const int i = j * 256 + t;
      const f32x4 o = o4[i], z = z4[i], r = r4[i & 31];
      const float sc = scale_s[i >> 5];
      f32x4 gg;
      gg.x = o.x * sc * r.x * silu_f(z.x);
      gg.y = o.y * sc * r.y * silu_f(z.y);
      gg.z = o.z * sc * r.z * silu_f(z.z);
      gg.w = o.w * sc * r.w * silu_f(z.w);
      g4w[i] = gg;
    }
  }
  __syncthreads();
  {
    const f32x4* __restrict__ g4 = (const f32x4*)smem;
    const int row0 = b * 8 + wave;
    const int row1 = b * 8 + 4 + wave;
    const f32x4* __restrict__ Wr0 = (const f32x4*)(Wout + (size_t)row0 * HID);
    const f32x4* __restrict__ Wr1 = (const f32x4*)(Wout + (size_t)row1 * HID);
    float a00 = 0.f, a01 = 0.f, a10 = 0.f, a11 = 0.f;
#pragma unroll
    for (int j = 0; j < 16; j += 2) {
      const int i0 = lane + j * 64, i1 = lane + (j + 1) * 64;
      const f32x4 g0 = g4[i0];
      const f32x4 g1 = g4[i1];
      const f32x4 w00 = __builtin_nontemporal_load(&Wr0[i0]);
      const f32x4 w01 = __builtin_nontemporal_load(&Wr0[i1]);
      const f32x4 w10 = __builtin_nontemporal_load(&Wr1[i0]);
      const f32x4 w11 = __builtin_nontemporal_load(&Wr1[i1]);
      a00 += w00.x * g0.x + w00.y * g0.y + w00.z * g0.z + w00.w * g0.w;
      a01 += w01.x * g1.x + w01.y * g1.y + w01.z * g1.z + w01.w * g1.w;
      a10 += w10.x * g0.x + w10.y * g0.y + w10.z * g0.z + w10.w * g0.w;
      a11 += w11.x * g1.x + w11.y * g1.y + w11.z * g1.z + w11.w * g1.w;
    }
    const float acc0 = wave_reduce_sum(a00 + a01);
    const float acc1 = wave_reduce_sum(a10 + a11);
    if (lane == 0) { dout[row0] = acc0; dout[row1] = acc1; }
  }
}

extern "C" void kernel_launch(void* const* d_in, const int* in_sizes, int n_in,
                              void* d_out, int out_size, void* d_ws, size_t ws_size,
                              hipStream_t stream) {
  const float* hs         = (const float*)d_in[0];
  const float* delta_state= (const float*)d_in[1];
  const float* conv_state = (const float*)d_in[2];
  const float* Wqkv       = (const float*)d_in[3];
  const float* Wz         = (const float*)d_in[4];
  const float* Wa         = (const float*)d_in[5];
  const float* Wb         = (const float*)d_in[6];
  const float* Wout       = (const float*)d_in[7];
  const float* conv_w     = (const float*)d_in[8];
  const float* A_log      = (const float*)d_in[9];
  const float* dt_bias    = (const float*)d_in[10];
  const float* rms_w      = (const float*)d_in[11];
  float* ws  = (float*)d_ws;
  float* out = (float*)d_out;

  // reset barrier counters every call (capture-safe, deterministic)
  hipMemsetAsync((char*)d_ws + CTR_QKVAB_B, 0, 256, stream);

  k_all<<<NGRID, 256, 0, stream>>>(hs, delta_state, conv_state, Wqkv, Wz, Wa,
                                   Wb, Wout, conv_w, A_log, dt_bias, rms_w,
                                   ws, out);
}

// Round 10
// 65.004 us; speedup vs baseline: 14.8985x; 14.8985x over previous
//
#include <hip/hip_runtime.h>
#include <math.h>

#define HID 4096
#define NH 32
#define DK 128
#define DV 128
#define NQKV 12288              // NH*DK*2 + NH*DV
#define ROWS1 16448             // NQKV + HID + NH + NH

// d_out layout: [result 4096 | S 32*128*128=524288 | new_conv_state 12288*3=36864]
#define OUT_S_OFF 4096
#define OUT_CONV_OFF 528384

// ws layout (floats): [qkv 12288 | z 4096 | a 32 | b 32 | o 4096]
#define WS_Z_OFF 12288
#define WS_A_OFF 16384
#define WS_B_OFF 16416
#define WS_O_OFF 16448

typedef float f32x4 __attribute__((ext_vector_type(4)));
typedef float f32x2 __attribute__((ext_vector_type(2)));

__device__ __forceinline__ float wave_reduce_sum(float x) {
#pragma unroll
  for (int off = 32; off > 0; off >>= 1) x += __shfl_xor(x, off, 64);
  return x;
}

__device__ __forceinline__ float silu_f(float x) {
  return x / (1.f + __expf(-x));
}

// Kernel 1: fused matvec for W_qkv, W_z, W_a, W_b against hs. One wave per row.
// hs staged in LDS; nt weight loads; conv_state epilogue for qkv rows.
__global__ __launch_bounds__(256) void k_matvec_in(
    const float* __restrict__ hs,
    const float* __restrict__ Wqkv, const float* __restrict__ Wz,
    const float* __restrict__ Wa, const float* __restrict__ Wb,
    const float* __restrict__ conv_state,
    float* __restrict__ ws, float* __restrict__ dout) {
  __shared__ __align__(16) float hls[HID];
  {
    f32x4* hl4 = (f32x4*)hls;
    const f32x4* h4 = (const f32x4*)hs;
#pragma unroll
    for (int m = 0; m < 4; ++m)
      hl4[m * 256 + threadIdx.x] = h4[m * 256 + threadIdx.x];
  }
  __syncthreads();

  const int wave = threadIdx.x >> 6, lane = threadIdx.x & 63;
  const int row = blockIdx.x * 4 + wave;
  const float* W;
  int r;
  if (row < NQKV) { W = Wqkv; r = row; }
  else if (row < NQKV + HID) { W = Wz; r = row - NQKV; }
  else if (row < NQKV + HID + NH) { W = Wa; r = row - (NQKV + HID); }
  else { W = Wb; r = row - (NQKV + HID + NH); }
  const f32x4* __restrict__ Wr = (const f32x4*)(W + (size_t)r * HID);
  const f32x4* __restrict__ hl4 = (const f32x4*)hls;
  float acc0 = 0.f, acc1 = 0.f;
#pragma unroll
  for (int j = 0; j < 16; j += 2) {
    const f32x4 w0 = __builtin_nontemporal_load(&Wr[lane + j * 64]);
    const f32x4 h0 = hl4[lane + j * 64];
    const f32x4 w1 = __builtin_nontemporal_load(&Wr[lane + (j + 1) * 64]);
    const f32x4 h1 = hl4[lane + (j + 1) * 64];
    acc0 += w0.x * h0.x + w0.y * h0.y + w0.z * h0.z + w0.w * h0.w;
    acc1 += w1.x * h1.x + w1.y * h1.y + w1.z * h1.z + w1.w * h1.w;
  }
  float acc = wave_reduce_sum(acc0 + acc1);
  if (lane == 0) {
    ws[row] = acc;
    if (row < NQKV) {
      dout[OUT_CONV_OFF + row * 3 + 0] = conv_state[row * 3 + 1];
      dout[OUT_CONV_OFF + row * 3 + 1] = conv_state[row * 3 + 2];
      dout[OUT_CONV_OFF + row * 3 + 2] = acc;
    }
  }
}

// Kernel 2: 1024 blocks; block b owns head h=b>>5 and v-rows vbase..vbase+3.
// Redundantly recomputes the head's conv+silu+norm scalars (L2-cached, cheap),
// then one wave per S-row: r1=S·kn, r2=S·qn, delta, S_new write (PLAIN store
// — nt store to a validated output is a post-timing-coherence hazard), o -> ws.
__global__ __launch_bounds__(256) void k_state(
    const float* __restrict__ delta_state, const float* __restrict__ conv_state,
    const float* __restrict__ conv_w, const float* __restrict__ A_log,
    const float* __restrict__ dt_bias,
    float* __restrict__ ws, float* __restrict__ dout) {
  const int bid = blockIdx.x;
  const int h = bid >> 5;
  const int vbase = (bid & 31) * 4;
  const int t = threadIdx.x;
  __shared__ __align__(16) float qn[DK];
  __shared__ __align__(16) float kn[DK];
  __shared__ float va4[4];
  __shared__ float s_eg, s_beta, s_kq, s_rq, s_rk;

  {
    const int seg = t >> 7, li = t & 127;
    const int row = seg * 4096 + h * 128 + li;
    const float c0 = conv_state[row * 3 + 0];
    const float c1 = conv_state[row * 3 + 1];
    const float c2 = conv_state[row * 3 + 2];
    const float w0 = conv_w[row * 4 + 0], w1 = conv_w[row * 4 + 1];
    const float w2 = conv_w[row * 4 + 2], w3 = conv_w[row * 4 + 3];
    const float co = w0 * c0 + w1 * c1 + w2 * c2 + w3 * ws[row];
    const float act = silu_f(co);
    if (seg == 0) qn[li] = act; else kn[li] = act;
  }
  if (t < 4) {
    const int row = 2 * 4096 + h * 128 + vbase + t;
    const float c0 = conv_state[row * 3 + 0];
    const float c1 = conv_state[row * 3 + 1];
    const float c2 = conv_state[row * 3 + 2];
    const float w0 = conv_w[row * 4 + 0], w1 = conv_w[row * 4 + 1];
    const float w2 = conv_w[row * 4 + 2], w3 = conv_w[row * 4 + 3];
    va4[t] = silu_f(w0 * c0 + w1 * c1 + w2 * c2 + w3 * ws[row]);
  }
  if (t == 4) {
    const float aa = ws[WS_A_OFF + h] + dt_bias[h];
    s_eg = __expf(-__expf(A_log[h]) * log1pf(__expf(aa)));
    s_beta = 1.f / (1.f + __expf(-ws[WS_B_OFF + h]));
  }
  __syncthreads();

  if (t < 64) {
    const float q0 = qn[t], q1 = qn[t + 64];
    const float k0 = kn[t], k1 = kn[t + 64];
    float sq = q0 * q0 + q1 * q1;
    float sk = k0 * k0 + k1 * k1;
    float dq = q0 * k0 + q1 * k1;
#pragma unroll
    for (int off = 32; off > 0; off >>= 1) {
      sq += __shfl_xor(sq, off, 64);
      sk += __shfl_xor(sk, off, 64);
      dq += __shfl_xor(dq, off, 64);
    }
    if (t == 0) {
      const float rq = rsqrtf(sq + 1e-6f) * 0.08838834764831845f; // *1/sqrt(DK)
      const float rk = rsqrtf(sk + 1e-6f);
      s_rq = rq; s_rk = rk;
      s_kq = dq * rq * rk;
    }
  }
  __syncthreads();
  if (t < 128) { qn[t] *= s_rq; kn[t] *= s_rk; }
  __syncthreads();

  const int w = t >> 6, lane = t & 63;
  const int v = vbase + w;
  const size_t roff = ((size_t)h * DV + v) * DK;
  const f32x2 s2 = __builtin_nontemporal_load(&((const f32x2*)(delta_state + roff))[lane]);
  const f32x2 kk = ((const f32x2*)kn)[lane];
  const f32x2 qq = ((const f32x2*)qn)[lane];
  float r1 = s2.x * kk.x + s2.y * kk.y;
  float r2 = s2.x * qq.x + s2.y * qq.y;
#pragma unroll
  for (int off = 32; off > 0; off >>= 1) {
    r1 += __shfl_xor(r1, off, 64);
    r2 += __shfl_xor(r2, off, 64);
  }
  const float eg = s_eg;
  const float dv_ = s_beta * (va4[w] - eg * r1);
  const float o = eg * r2 + dv_ * s_kq;
  f32x2 out2;
  out2.x = eg * s2.x + dv_ * kk.x;
  out2.y = eg * s2.y + dv_ * kk.y;
  ((f32x2*)(dout + OUT_S_OFF + roff))[lane] = out2;   // plain store
  if (lane == 0) ws[WS_O_OFF + h * DV + v] = o;
}

// Kernel 3: slim gating prologue (parallel scale, f32x4 global->LDS), then
// result = W_out @ gated, one wave per row.
__global__ __launch_bounds__(256) void k_matvec_out(
    const float* __restrict__ Wout, const float* __restrict__ rms_w,
    float* __restrict__ ws, float* __restrict__ dout) {
  __shared__ __align__(16) float g[HID];
  __shared__ float scale[NH];
  const int t = threadIdx.x;
  {
    const int hh = t >> 3, sub = t & 7;
    const f32x4* o4 = (const f32x4*)(ws + WS_O_OFF + hh * 128 + sub * 16);
    float ss = 0.f;
#pragma unroll
    for (int j = 0; j < 4; ++j) {
      const f32x4 o = o4[j];
      ss += o.x * o.x + o.y * o.y + o.z * o.z + o.w * o.w;
    }
    ss += __shfl_xor(ss, 1, 64);
    ss += __shfl_xor(ss, 2, 64);
    ss += __shfl_xor(ss, 4, 64);
    if (sub == 0) scale[hh] = rsqrtf(ss * (1.f / 128.f) + 1e-6f);
  }
  __syncthreads();
  {
    const f32x4* o4 = (const f32x4*)(ws + WS_O_OFF);
    const f32x4* z4 = (const f32x4*)(ws + WS_Z_OFF);
    const f32x4* r4 = (const f32x4*)rms_w;
    f32x4* g4 = (f32x4*)g;
#pragma unroll
    for (int j = 0; j < 4; ++j) {
      const int i = j * 256 + t;
      const f32x4 o = o4[i], z = z4[i], r = r4[i & 31];
      const float sc = scale[i >> 5];
      f32x4 gg;
      gg.x = o.x * sc * r.x * silu_f(z.x);
      gg.y = o.y * sc * r.y * silu_f(z.y);
      gg.z = o.z * sc * r.z * silu_f(z.z);
      gg.w = o.w * sc * r.w * silu_f(z.w);
      g4[i] = gg;
    }
  }
  __syncthreads();

  const int wave = t >> 6, lane = t & 63;
  const int row = blockIdx.x * 4 + wave;
  const f32x4* __restrict__ Wr = (const f32x4*)(Wout + (size_t)row * HID);
  const f32x4* __restrict__ g4 = (const f32x4*)g;
  float acc0 = 0.f, acc1 = 0.f;
#pragma unroll
  for (int j = 0; j < 16; j += 2) {
    const f32x4 w0 = __builtin_nontemporal_load(&Wr[lane + j * 64]);
    const f32x4 gg0 = g4[lane + j * 64];
    const f32x4 w1 = __builtin_nontemporal_load(&Wr[lane + (j + 1) * 64]);
    const f32x4 gg1 = g4[lane + (j + 1) * 64];
    acc0 += w0.x * gg0.x + w0.y * gg0.y + w0.z * gg0.z + w0.w * gg0.w;
    acc1 += w1.x * gg1.x + w1.y * gg1.y + w1.z * gg1.z + w1.w * gg1.w;
  }
  const float acc = wave_reduce_sum(acc0 + acc1);
  if (lane == 0) dout[row] = acc;
}

extern "C" void kernel_launch(void* const* d_in, const int* in_sizes, int n_in,
                              void* d_out, int out_size, void* d_ws, size_t ws_size,
                              hipStream_t stream) {
  const float* hs         = (const float*)d_in[0];
  const float* delta_state= (const float*)d_in[1];
  const float* conv_state = (const float*)d_in[2];
  const float* Wqkv       = (const float*)d_in[3];
  const float* Wz         = (const float*)d_in[4];
  const float* Wa         = (const float*)d_in[5];
  const float* Wb         = (const float*)d_in[6];
  const float* Wout       = (const float*)d_in[7];
  const float* conv_w     = (const float*)d_in[8];
  const float* A_log      = (const float*)d_in[9];
  const float* dt_bias    = (const float*)d_in[10];
  const float* rms_w      = (const float*)d_in[11];
  float* ws  = (float*)d_ws;
  float* out = (float*)d_out;

  k_matvec_in<<<ROWS1 / 4, 256, 0, stream>>>(hs, Wqkv, Wz, Wa, Wb, conv_state,
                                             ws, out);
  k_state<<<NH * 32, 256, 0, stream>>>(delta_state, conv_state, conv_w, A_log,
                                       dt_bias, ws, out);
  k_matvec_out<<<HID / 4, 256, 0, stream>>>(Wout, rms_w, ws, out);
}